// Round 2
// 961.593 us; speedup vs baseline: 1.0310x; 1.0310x over previous
//
#include <hip/hip_runtime.h>
#include <stdint.h>

// Baum-Welch forward-backward posteriors (log_gamma), MI355X gfx950.
//
// R5 -> R6 (theory: per-step serial latency, not throughput):
//  - Wave-owns-outputs layout: wave g owns states [32g,32g+32); lane (oc=c&7,
//    ic=c>>3) computes 4 outputs over a 32-input chunk (keeps 4x reuse of the
//    staged vector: still 8 x ds_read_b128 per lane per step).
//  - Cross-chunk reduce = 3 pipelined shfl_xor stages (8/16/32) instead of the
//    part[8][K] LDS round-trip => ONE barrier per step (ping-pong avec).
//  - avec chunks padded to 36 floats: the 8 broadcast groups of a wave's b128
//    read start at banks 4*(ic+m)%32 -> conflict-free.
//  - Uniform rescale via rcp(prev_staged[0]) (broadcast LDS read, guarded
//    against underflow): any block-uniform scale cancels in gamma's per-(n,t)
//    normalization, and the ratio form is self-correcting.
//  - bwd stores RAW scaled alpha*beta; shuffle+atomic+log denominator chain
//    deleted from the recurrence. A 3rd streaming kernel (268 MB, ~50us)
//    log-normalizes rows. Output rows batched 8-at-a-time via rbuf (f4 flush).
//  - In-loop barrier = "s_waitcnt lgkmcnt(0)" + s_barrier (no vmcnt drain):
//    no intra-step cross-thread VMEM communication exists (bwd reads rows < t,
//    flushes rows >= t), so prefetches/stores stay in flight across steps.

#define NB 256
#define TT 512
#define KK 256
#define VV 4096
#define LOG2E 1.44269504088896f
#define LN2 0.693147180559945f

typedef float f2 __attribute__((ext_vector_type(2)));
typedef float f4 __attribute__((ext_vector_type(4)));

__device__ __forceinline__ void bar_lds() {
  // Workgroup barrier that drains LDS only (keeps global loads/stores in
  // flight across steps). Learn_hip-verified pattern.
  asm volatile("s_waitcnt lgkmcnt(0)" ::: "memory");
  __builtin_amdgcn_s_barrier();
}

// MODE 0: forward (stores scaled alpha rows to gout).
// MODE 1: backward (overwrites gout rows with scaled alpha*beta, high t first).
template <int MODE>
__global__ __launch_bounds__(512, 2) void hmm_recur(
    const float* __restrict__ lpi, const float* __restrict__ lA,
    const float* __restrict__ lB, const int* __restrict__ obs,
    float* __restrict__ gout) {
  const int n = blockIdx.x;
  const int tid = threadIdx.x;  // 0..511
  const int g = tid >> 6;       // wave id: owns output states [32g, 32g+32)
  const int c = tid & 63;
  const int oc = c & 7;         // output sub-slot
  const int ic = c >> 3;        // input chunk: [32*ic, 32*ic+32)
  const bool lead = (c < 32);   // writer lanes; p = c>>3 in 0..3, jw = 32g+c
  const int jw = g * 32 + c;    // writer-lane output state (valid when lead)

  __shared__ int obs_s[TT];                      // 2 KB
  __shared__ __align__(16) float avec[2][288];   // ping-pong staged vector,
                                                 // 8 chunks of 36 (32 + 4 pad)
  __shared__ __align__(16) float rbuf[16][KK];   // 16 KB batched output rows

  for (int i = tid; i < TT; i += 512) obs_s[i] = obs[n * TT + i];

  // Register-resident exp(A) fragments:
  // apair[p][k] covers output jo = 32g+oc+8p, inputs i0 = 32*ic+2k (+1).
  // fwd needs A columns (A[i][jo]); bwd needs A rows (A[jo][i]).
  f2 apair[4][16];
#pragma unroll
  for (int p = 0; p < 4; ++p) {
    const int jo = g * 32 + oc + 8 * p;
#pragma unroll
    for (int k = 0; k < 16; ++k) {
      const int i0 = 32 * ic + 2 * k;
      float e0, e1;
      if (MODE == 0) {
        e0 = lA[(size_t)i0 * KK + jo];
        e1 = lA[(size_t)(i0 + 1) * KK + jo];
      } else {
        e0 = lA[(size_t)jo * KK + i0];
        e1 = lA[(size_t)jo * KK + i0 + 1];
      }
      f2 pr;
      pr[0] = exp2f(e0 * LOG2E);
      pr[1] = exp2f(e1 * LOG2E);
      apair[p][k] = pr;
    }
  }
  __syncthreads();  // obs_s ready

  // Full dot for this lane's 4 outputs over the staged (padded) vector:
  // 8 x ds_read_b128 (conflict-free via 36-float chunk pad), 64 pk_fma,
  // then 3 shfl_xor stages across the 8 input-chunk replicas.
  auto dot4r = [&](const float* src, float s[4]) {
    const f4* s4 = (const f4*)(src + 36 * ic);
    f2 a0 = (f2)0.f, a1 = (f2)0.f, a2 = (f2)0.f, a3 = (f2)0.f;
#pragma unroll
    for (int m = 0; m < 8; ++m) {
      const f4 x = s4[m];
      f2 xl; xl[0] = x[0]; xl[1] = x[1];
      f2 xh; xh[0] = x[2]; xh[1] = x[3];
      a0 += xl * apair[0][2 * m]; a0 += xh * apair[0][2 * m + 1];
      a1 += xl * apair[1][2 * m]; a1 += xh * apair[1][2 * m + 1];
      a2 += xl * apair[2][2 * m]; a2 += xh * apair[2][2 * m + 1];
      a3 += xl * apair[3][2 * m]; a3 += xh * apair[3][2 * m + 1];
    }
    s[0] = a0[0] + a0[1];
    s[1] = a1[0] + a1[1];
    s[2] = a2[0] + a2[1];
    s[3] = a3[0] + a3[1];
#pragma unroll
    for (int msk = 8; msk <= 32; msk <<= 1) {
      s[0] += __shfl_xor(s[0], msk);
      s[1] += __shfl_xor(s[1], msk);
      s[2] += __shfl_xor(s[2], msk);
      s[3] += __shfl_xor(s[3], msk);
    }
  };

  if (MODE == 0) {
    // ---- forward ----
    float bl = 0.f;  // prefetched raw lB for the next step
    if (lead) {
      const int o0 = obs_s[0];
      float u = exp2f((lpi[jw] + lB[(size_t)jw * VV + o0]) * LOG2E);
      avec[0][36 * g + c] = u;
      rbuf[0][jw] = u;
      bl = lB[(size_t)jw * VV + obs_s[1]];
    }
    __syncthreads();

#pragma unroll 1
    for (int t = 1; t < TT; ++t) {
      float bln = 0.f;
      if (lead && t + 1 < TT) bln = lB[(size_t)jw * VV + obs_s[t + 1]];
      const float* src = avec[(t + 1) & 1];
      const float ref = fmaxf(src[0], 1e-35f);  // broadcast uniform scale
      float s[4];
      dot4r(src, s);
      if (lead) {
        const int p = c >> 3;
        float sv = p == 0 ? s[0] : p == 1 ? s[1] : p == 2 ? s[2] : s[3];
        float u = sv * __builtin_amdgcn_rcpf(ref) * exp2f(bl * LOG2E);
        avec[t & 1][36 * g + c] = u;
        rbuf[t & 15][jw] = u;
      }
      bl = bln;
      bar_lds();
      if ((t & 7) == 7) {
        // flush alpha rows t-7..t: thread (g,c) stores row t-7+g, cols 4c..
        const int row = t - 7 + g;
        const f4 v = *(const f4*)&rbuf[row & 15][c * 4];
        *(f4*)&gout[((size_t)n * TT + row) * KK + c * 4] = v;
      }
    }
  } else {
    // ---- backward: overwrite gout rows with scaled alpha*beta ----
    float bl = 0.f, avp = 0.f;  // prefetched raw lB and alpha row
    if (lead) {
      const int oT = obs_s[TT - 1];
      const size_t rb = (size_t)n * TT * KK;
      float av = gout[rb + (size_t)(TT - 1) * KK + jw];  // alpha_{T-1}, beta=1
      avec[1][36 * g + c] = exp2f(lB[(size_t)jw * VV + oT] * LOG2E);
      rbuf[15][jw] = av;  // gg row T-1 (slot 511 & 15 = 15)
      avp = gout[rb + (size_t)(TT - 2) * KK + jw];
      bl = lB[(size_t)jw * VV + obs_s[TT - 2]];
    }
    __syncthreads();

#pragma unroll 1
    for (int t = TT - 2; t >= 0; --t) {
      float avn = 0.f, bln = 0.f;
      if (lead && t > 0) {
        avn = gout[((size_t)n * TT + (t - 1)) * KK + jw];
        bln = lB[(size_t)jw * VV + obs_s[t - 1]];
      }
      const float* src = avec[(t + 1) & 1];  // staged w_{t+1}
      const float ref = fmaxf(src[0], 1e-35f);
      float s[4];
      dot4r(src, s);
      if (lead) {
        const int p = c >> 3;
        float sv = p == 0 ? s[0] : p == 1 ? s[1] : p == 2 ? s[2] : s[3];
        float beta = sv * __builtin_amdgcn_rcpf(ref);        // scaled beta_t
        avec[t & 1][36 * g + c] = beta * exp2f(bl * LOG2E);  // staged w_t
        rbuf[t & 15][jw] = avp * beta;                       // gg row t
      }
      avp = avn;
      bl = bln;
      bar_lds();
      if ((t & 7) == 0) {
        // flush gg rows t..t+7 (rows >= t only; prefetches read rows < t)
        const int row = t + g;
        const f4 v = *(const f4*)&rbuf[row & 15][c * 4];
        *(f4*)&gout[((size_t)n * TT + row) * KK + c * 4] = v;
      }
    }
  }
}

// Pass 3: log-normalize each (n,t) row of 256 positive scaled alpha*beta
// values in place: out = (log2(v) - log2(sum v)) * ln2. Pure streaming,
// 268 MB total traffic.
__global__ __launch_bounds__(256) void gamma_norm(float* __restrict__ gout) {
  const int wave = blockIdx.x * 4 + (threadIdx.x >> 6);
  const int c = threadIdx.x & 63;
  const int stride = gridDim.x * 4;
#pragma unroll 1
  for (int row = wave; row < NB * TT; row += stride) {
    float* p = gout + (size_t)row * KK + c * 4;
    const f4 v = *(const f4*)p;
    float s = (v[0] + v[1]) + (v[2] + v[3]);
#pragma unroll
    for (int d = 1; d < 64; d <<= 1) s += __shfl_xor(s, d);
    const float lg = __log2f(s);
    f4 o;
    o[0] = (__log2f(v[0]) - lg) * LN2;
    o[1] = (__log2f(v[1]) - lg) * LN2;
    o[2] = (__log2f(v[2]) - lg) * LN2;
    o[3] = (__log2f(v[3]) - lg) * LN2;
    *(f4*)p = o;
  }
}

extern "C" void kernel_launch(void* const* d_in, const int* in_sizes, int n_in,
                              void* d_out, int out_size, void* d_ws, size_t ws_size,
                              hipStream_t stream) {
  const float* lpi = (const float*)d_in[0];
  const float* lA = (const float*)d_in[1];
  const float* lB = (const float*)d_in[2];
  const int* obs = (const int*)d_in[3];
  float* gout = (float*)d_out;
  (void)d_ws; (void)ws_size;  // deliberately unused

  hmm_recur<0><<<NB, 512, 0, stream>>>(lpi, lA, lB, obs, gout);
  hmm_recur<1><<<NB, 512, 0, stream>>>(lpi, lA, lB, obs, gout);
  gamma_norm<<<2048, 256, 0, stream>>>(gout);
}